// Round 15
// baseline (225.509 us; speedup 1.0000x reference)
//
#include <hip/hip_runtime.h>
#include <hip/hip_bf16.h>
#include <stdint.h>

#define N_NODES 50000
#define N_EDGES 800000
#define D 64
#define VROWS 50048   // 782 tiles * 64 rows, rounded up for unmasked A-loads
#define CVT_BLOCKS 3125   // N_NODES*64 / (256*4) == N_EDGES / 256 exactly
#define CAP 64            // fixed bucket capacity; P(Poisson(16) > 64) ~ 1e-18

typedef __hip_bfloat16 bf16;
typedef __bf16 bf16x8 __attribute__((ext_vector_type(8)));
typedef float  f32x4  __attribute__((ext_vector_type(4)));

__device__ __forceinline__ float bu2f(unsigned short u) {
    unsigned int w = ((unsigned int)u) << 16;
    return __builtin_bit_cast(float, w);
}
__device__ __forceinline__ unsigned short f2bu(float f) {
    bf16 h = __float2bfloat16(f);           // RTNE
    return __builtin_bit_cast(unsigned short, h);
}
__device__ __forceinline__ float ldf(const void* p, size_t i, bool f32mode) {
    if (f32mode) return ((const float*)p)[i];
    return bu2f(((const unsigned short*)p)[i]);
}
__device__ __forceinline__ void stf(void* p, size_t i, float v, bool f32mode) {
    if (f32mode) ((float*)p)[i] = v;
    else ((unsigned short*)p)[i] = f2bu(v);
}
__device__ __forceinline__ int ldidx(const int* ei, size_t e, int row, bool i64mode) {
    if (i64mode) return ei[((size_t)row * N_EDGES + e) * 2];  // low word, LE
    return ei[(size_t)row * N_EDGES + e];
}
__device__ __forceinline__ void unpack8(uint4 v, float* f) {
    f[0] = bu2f(v.x & 0xffff); f[1] = bu2f(v.x >> 16);
    f[2] = bu2f(v.y & 0xffff); f[3] = bu2f(v.y >> 16);
    f[4] = bu2f(v.z & 0xffff); f[5] = bu2f(v.z >> 16);
    f[6] = bu2f(v.w & 0xffff); f[7] = bu2f(v.w >> 16);
}

// ---------------------------------------------------------------------------
// Kernel A (R24: tiny init). 196 blocks: block 0 wave 0 does the proven
// dtype sniff entirely in-wave (shfl totals -> every lane knows f32m, no
// LDS/sync needed) and publishes params; all blocks zero a 256-int slice of
// counts. The heavy streaming (x convert, endpoint extraction) moved into
// histconv's atomic-latency shadow.
// ---------------------------------------------------------------------------
__global__ __launch_bounds__(256) void initA_kernel(
    const void* __restrict__ x, const int* __restrict__ ei,
    const void* __restrict__ W2, const void* __restrict__ b1,
    const void* __restrict__ b2,
    int* __restrict__ flags, unsigned short* __restrict__ w2bf,
    float* __restrict__ b1f, float* __restrict__ b2fp,
    int* __restrict__ counts)
{
    int tid = threadIdx.x;
    if (blockIdx.x == 0 && tid < 64) {
        const unsigned short* u = (const unsigned short*)x;
        int weird = 0, zeros = 0;
        #pragma unroll
        for (int k = tid; k < 128; k += 64) {
            int ex = (u[2 * k] >> 7) & 0xFF;
            if (ex < 90 || ex > 160) ++weird;
            if (ei[2 * k + 1] == 0) ++zeros;
        }
        #pragma unroll
        for (int off = 1; off < 64; off <<= 1) {
            weird += __shfl_xor(weird, off, 64);
            zeros += __shfl_xor(zeros, off, 64);
        }
        bool f32m = (weird > 32);
        w2bf[tid] = f2bu(ldf(W2, tid, f32m));
        b1f[tid]  = ldf(b1, tid, f32m);
        if (tid == 0) {
            flags[0] = f32m ? 1 : 0;
            flags[1] = (zeros > 120) ? 1 : 0;
            b2fp[0] = ldf(b2, 0, f32m);
        }
    }
    int i = blockIdx.x * 256 + tid;
    if (i < N_NODES) counts[i] = 0;
}

// ---------------------------------------------------------------------------
// Kernel B (R24: histconv = XCD-sharded histfill + x-conversion + endpoint
// extraction fused). histfill is atomic-latency-bound with huge BW headroom
// (R10 PMC: 19% HBM, 7% VALU) — the streaming work rides in its shadow:
//   - blocks < 3125 convert their 1024-element x slice to bf16 xbf
//   - grp==0 blocks extract dst16/src16 (single coverage) for eid-major edge
//   - all blocks run the proven XCD-sharded scatter (R11 lesson: homed
//     writes; R12 lesson: 8 edges/thread vectorized-ish, 3128 blocks)
// Static slots d*CAP; atomic rank IS the slot; r<CAP is memory-safety only.
// ---------------------------------------------------------------------------
__global__ __launch_bounds__(256) void histconv_kernel(
    const void* __restrict__ x, const int* __restrict__ ei,
    const int* __restrict__ flags,
    int* __restrict__ counts, unsigned short* __restrict__ sarr,
    unsigned short* __restrict__ xbf,
    unsigned short* __restrict__ dst16, unsigned short* __restrict__ src16)
{
    bool f32m = flags[0] != 0;
    bool i64m = flags[1] != 0;
    int tid = threadIdx.x;
    int bid = blockIdx.x;

    // ---- x conversion slice (streams under the atomic stalls below) ----
    if (bid < CVT_BLOCKS) {
        size_t idx4 = (size_t)bid * 256 + tid;
        if (f32m) {
            float4 fv = ((const float4*)x)[idx4];
            ushort4 o;
            o.x = f2bu(fv.x); o.y = f2bu(fv.y); o.z = f2bu(fv.z); o.w = f2bu(fv.w);
            ((ushort4*)xbf)[idx4] = o;
        } else {
            ((uint2*)xbf)[idx4] = ((const uint2*)x)[idx4];
        }
    }

    // ---- XCD-sharded histfill over raw ei (R10-proven read pattern) ----
    int region = bid >> 3;
    int grp    = bid & 7;
    int e0 = region * 2048 + tid * 8;
    #pragma unroll
    for (int k = 0; k < 8; ++k) {
        int e = e0 + k;
        if (e >= N_EDGES) break;
        int d = ldidx(ei, e, 1, i64m);
        int s = ldidx(ei, e, 0, i64m);
        if (grp == 0) {   // single-coverage endpoint extraction for edge
            dst16[e] = (unsigned short)d;
            src16[e] = (unsigned short)s;
        }
        if (((d >> 6) & 7) != grp) continue;
        int r = atomicAdd(&counts[d], 1);
        if (r < CAP)
            sarr[(size_t)d * CAP + r] = (unsigned short)s;
    }
}

// ---------------------------------------------------------------------------
// Kernel 2 (proven R15 gather, u16 sarr slots, static bucket base). One wave
// per node; lane = (f8, slot); one uint4 wave-load = 8 edge rows; 2 loads /
// 16 edges in flight; cross-slot shfl fold at the end.
// ---------------------------------------------------------------------------
__global__ __launch_bounds__(256) void gather_kernel(
    const unsigned short* __restrict__ xbf,
    const int* __restrict__ counts, const unsigned short* __restrict__ sarr,
    unsigned short* __restrict__ vtab)
{
    int w    = (blockIdx.x * 256 + threadIdx.x) >> 6;   // node id
    int lane = threadIdx.x & 63;
    if (w >= N_NODES) return;
    int cnt = counts[w];
    if (cnt > CAP) cnt = CAP;
    int beg = w * CAP, end = beg + cnt;
    int f8   = lane & 7;    // feature chunk (8 feats = 16 B)
    int slot = lane >> 3;   // edge slot 0..7

    float acc[8] = {0.f, 0.f, 0.f, 0.f, 0.f, 0.f, 0.f, 0.f};
    if (slot == 0) {   // self row, added exactly once
        uint4 q = ((const uint4*)xbf)[(size_t)w * 8 + f8];
        unpack8(q, acc);
    }

    int j = beg;
    for (; j + 16 <= end; j += 16) {
        int s0 = sarr[j + slot];
        int s1 = sarr[j + 8 + slot];
        uint4 q0 = ((const uint4*)xbf)[(size_t)s0 * 8 + f8];
        uint4 q1 = ((const uint4*)xbf)[(size_t)s1 * 8 + f8];
        float f0[8], f1[8];
        unpack8(q0, f0);
        unpack8(q1, f1);
        #pragma unroll
        for (int i = 0; i < 8; ++i) acc[i] += f0[i] + f1[i];
    }
    for (; j < end; j += 8) {
        int e = j + slot;
        bool ok = e < end;
        int s = sarr[ok ? e : beg];
        uint4 q = ((const uint4*)xbf)[(size_t)s * 8 + f8];
        float f[8];
        unpack8(q, f);
        if (ok) {
            #pragma unroll
            for (int i = 0; i < 8; ++i) acc[i] += f[i];
        }
    }

    // fold the 8 slots (lanes with equal f8) together
    #pragma unroll
    for (int i = 0; i < 8; ++i) {
        acc[i] += __shfl_xor(acc[i], 8, 64);
        acc[i] += __shfl_xor(acc[i], 16, 64);
        acc[i] += __shfl_xor(acc[i], 32, 64);
    }

    if (slot == 0) {
        uint4 o;
        o.x = (unsigned int)f2bu(acc[0]) | ((unsigned int)f2bu(acc[1]) << 16);
        o.y = (unsigned int)f2bu(acc[2]) | ((unsigned int)f2bu(acc[3]) << 16);
        o.z = (unsigned int)f2bu(acc[4]) | ((unsigned int)f2bu(acc[5]) << 16);
        o.w = (unsigned int)f2bu(acc[6]) | ((unsigned int)f2bu(acc[7]) << 16);
        ((uint4*)vtab)[(size_t)w * 8 + f8] = o;
    }
}

// ---------------------------------------------------------------------------
// Kernel 3: MFMA node transform (exact R7-proven body). One wave = 16 nodes.
// vtab aliases p_src: each wave reads its own 16 rows before overwriting.
// ---------------------------------------------------------------------------
__global__ __launch_bounds__(256) void nodemm_kernel(
    const unsigned short* vtab,
    const void* __restrict__ W_enc, const void* __restrict__ b_enc,
    const void* __restrict__ W1,
    unsigned short* p_src, unsigned short* p_dst,
    const float* __restrict__ b1f, const int* __restrict__ flags)
{
    __shared__ unsigned short wtWe[64 * 72];
    __shared__ unsigned short wtWa[64 * 72];
    __shared__ unsigned short wtWb[64 * 72];
    __shared__ float benc[64];
    __shared__ unsigned short ebuf[4][16 * 72];

    bool f32m = flags[0] != 0;
    int tid = threadIdx.x;
    for (int t = tid; t < 4096; t += 256) {
        int i = t >> 6, j = t & 63;             // W[i][j], i=k(in), j=n(out)
        wtWe[j * 72 + i] = f2bu(ldf(W_enc, t, f32m));
        wtWa[j * 72 + i] = f2bu(ldf(W1, t, f32m));
        wtWb[j * 72 + i] = f2bu(ldf(W1, 4096 + t, f32m));
    }
    if (tid < 64) benc[tid] = ldf(b_enc, tid, f32m);
    __syncthreads();

    int wave = tid >> 6;
    int lane = tid & 63;
    int lo   = lane & 15;
    int quad = lane >> 4;
    unsigned short* eb = ebuf[wave];
    int base = blockIdx.x * 64 + wave * 16;

    bf16x8 av0 = *(const bf16x8*)&vtab[(size_t)(base + lo) * D + quad * 8];
    bf16x8 av1 = *(const bf16x8*)&vtab[(size_t)(base + lo) * D + 32 + quad * 8];

    f32x4 z = {0.f, 0.f, 0.f, 0.f};
    f32x4 acc1[4] = {z, z, z, z};
    #pragma unroll
    for (int nt = 0; nt < 4; ++nt) {
        bf16x8 b0  = *(const bf16x8*)&wtWe[(nt * 16 + lo) * 72 + quad * 8];
        bf16x8 b1v = *(const bf16x8*)&wtWe[(nt * 16 + lo) * 72 + 32 + quad * 8];
        acc1[nt] = __builtin_amdgcn_mfma_f32_16x16x32_bf16(av0, b0, acc1[nt], 0, 0, 0);
        acc1[nt] = __builtin_amdgcn_mfma_f32_16x16x32_bf16(av1, b1v, acc1[nt], 0, 0, 0);
    }
    #pragma unroll
    for (int nt = 0; nt < 4; ++nt) {
        float bias = benc[nt * 16 + lo];
        #pragma unroll
        for (int r = 0; r < 4; ++r) {
            int m = quad * 4 + r;
            float ev = fmaxf(acc1[nt][r] + bias, 0.f);
            eb[m * 72 + nt * 16 + lo] = f2bu(ev);
        }
    }

    bf16x8 ae0 = *(const bf16x8*)&eb[lo * 72 + quad * 8];
    bf16x8 ae1 = *(const bf16x8*)&eb[lo * 72 + 32 + quad * 8];

    f32x4 acc2[4] = {z, z, z, z};
    f32x4 acc3[4] = {z, z, z, z};
    #pragma unroll
    for (int nt = 0; nt < 4; ++nt) {
        bf16x8 ba0 = *(const bf16x8*)&wtWa[(nt * 16 + lo) * 72 + quad * 8];
        bf16x8 ba1 = *(const bf16x8*)&wtWa[(nt * 16 + lo) * 72 + 32 + quad * 8];
        bf16x8 bb0 = *(const bf16x8*)&wtWb[(nt * 16 + lo) * 72 + quad * 8];
        bf16x8 bb1 = *(const bf16x8*)&wtWb[(nt * 16 + lo) * 72 + 32 + quad * 8];
        acc2[nt] = __builtin_amdgcn_mfma_f32_16x16x32_bf16(ae0, ba0, acc2[nt], 0, 0, 0);
        acc2[nt] = __builtin_amdgcn_mfma_f32_16x16x32_bf16(ae1, ba1, acc2[nt], 0, 0, 0);
        acc3[nt] = __builtin_amdgcn_mfma_f32_16x16x32_bf16(ae0, bb0, acc3[nt], 0, 0, 0);
        acc3[nt] = __builtin_amdgcn_mfma_f32_16x16x32_bf16(ae1, bb1, acc3[nt], 0, 0, 0);
    }
    #pragma unroll
    for (int nt = 0; nt < 4; ++nt) {
        float b1v = b1f[nt * 16 + lo];
        #pragma unroll
        for (int r = 0; r < 4; ++r) {
            int node = base + quad * 4 + r;
            if (node < N_NODES) {
                size_t idx = (size_t)node * D + nt * 16 + lo;
                p_src[idx] = f2bu(acc2[nt][r] + b1v);   // fold b1
                p_dst[idx] = f2bu(acc3[nt][r]);
            }
        }
    }
}

// ---------------------------------------------------------------------------
// Kernel 4 (proven R23: EID-MAJOR edge scorer). One wave = 16 consecutive
// edges (800000 = 50000 waves * 16 exactly). Random p_src/p_dst row reads
// (L3-resident), coalesced out[e] stores.
// ---------------------------------------------------------------------------
__global__ __launch_bounds__(256) void edge_kernel(
    const unsigned short* __restrict__ p_src,
    const unsigned short* __restrict__ p_dst,
    const unsigned short* __restrict__ src16,
    const unsigned short* __restrict__ dst16,
    const unsigned short* __restrict__ w2bf, const float* __restrict__ b2fp,
    void* __restrict__ out, const int* __restrict__ flags)
{
    bool f32m = flags[0] != 0;
    int wid  = (blockIdx.x * 256 + threadIdx.x) >> 6;   // wave id 0..49999
    int lane = threadIdx.x & 63;
    int e_base = wid * 16;
    if (e_base >= N_EDGES) return;
    int g   = lane >> 3;   // edge slot within round
    int sub = lane & 7;    // feature chunk (8 feats)

    uint4 w2v = ((const uint4*)w2bf)[sub];
    float w2[8];
    unpack8(w2v, w2);
    float bb = b2fp[0];

    int e0 = e_base + g;
    int e1 = e_base + 8 + g;
    int s0 = src16[e0], d0 = dst16[e0];
    int s1 = src16[e1], d1 = dst16[e1];

    uint4 qs0 = ((const uint4*)p_src)[(size_t)s0 * 8 + sub];
    uint4 qd0 = ((const uint4*)p_dst)[(size_t)d0 * 8 + sub];
    uint4 qs1 = ((const uint4*)p_src)[(size_t)s1 * 8 + sub];
    uint4 qd1 = ((const uint4*)p_dst)[(size_t)d1 * 8 + sub];
    float fs0[8], fd0[8], fs1[8], fd1[8];
    unpack8(qs0, fs0);
    unpack8(qd0, fd0);
    unpack8(qs1, fs1);
    unpack8(qd1, fd1);

    float c0 = 0.f, c1 = 0.f;
    #pragma unroll
    for (int i = 0; i < 8; ++i) {
        c0 += fmaxf(fs0[i] + fd0[i], 0.f) * w2[i];
        c1 += fmaxf(fs1[i] + fd1[i], 0.f) * w2[i];
    }
    c0 += __shfl_xor(c0, 1, 64);
    c0 += __shfl_xor(c0, 2, 64);
    c0 += __shfl_xor(c0, 4, 64);
    c1 += __shfl_xor(c1, 1, 64);
    c1 += __shfl_xor(c1, 2, 64);
    c1 += __shfl_xor(c1, 4, 64);
    if (sub == 0) {
        stf(out, e0, c0 + bb, f32m);   // 8 consecutive eids per round:
        stf(out, e1, c1 + bb, f32m);   // coalesced 32B segments
    }
}

// ---------------------------------------------------------------------------
extern "C" void kernel_launch(void* const* d_in, const int* in_sizes, int n_in,
                              void* d_out, int out_size, void* d_ws, size_t ws_size,
                              hipStream_t stream)
{
    const void* x     = d_in[0];
    const int*  ei    = (const int*)d_in[1];
    const void* W_enc = d_in[2];
    const void* b_enc = d_in[3];
    const void* W1    = d_in[4];
    const void* b1    = d_in[5];
    const void* W2    = d_in[6];
    const void* b2    = d_in[7];

    const size_t NTv  = (size_t)VROWS * D;     // 3,203,072 elements
    const size_t NCAP = (size_t)N_NODES * CAP; // 3,200,000 slots
    // ws layout (~29.2 MB):
    unsigned short* p_src = (unsigned short*)d_ws;       // 6.41 MB (aliases vtab)
    unsigned short* p_dst = p_src + NTv;                 // 6.41 MB
    unsigned short* xbf   = p_dst + NTv;                 // 6.41 MB (bf16 x table)
    unsigned short* sarr  = xbf + NTv;                   // 6.40 MB (u16 src per slot)
    float* b1f     = (float*)(sarr + NCAP);              // 256 B
    unsigned short* w2bf = (unsigned short*)(b1f + 64);  // 128 B
    float* b2fp    = (float*)(w2bf + 64);                // 16 B
    int*   counts  = (int*)(b2fp + 4);                   // 200 KB
    int*   flags   = counts + N_NODES;                   // 32 B (padded for align)
    unsigned short* dst16 = (unsigned short*)(flags + 8); // 1.6 MB (16B-aligned)
    unsigned short* src16 = dst16 + N_EDGES;             // 1.6 MB

    unsigned short* vtab = p_src;   // alias: v-rows live here until nodemm

    const int NBLKA = (N_NODES + 255) / 256;   // 196
    initA_kernel<<<NBLKA, 256, 0, stream>>>(x, ei, W2, b1, b2,
                                            flags, w2bf, b1f, b2fp, counts);

    const int HF_BLOCKS = ((N_EDGES + 2047) / 2048) * 8;   // 391*8 = 3128
    histconv_kernel<<<HF_BLOCKS, 256, 0, stream>>>(x, ei, flags, counts, sarr,
                                                   xbf, dst16, src16);

    const int NWB = (N_NODES * 64 + 255) / 256;  // 12500 (1 wave/node)
    gather_kernel<<<NWB, 256, 0, stream>>>(xbf, counts, sarr, vtab);
    nodemm_kernel<<<(N_NODES + 63) / 64, 256, 0, stream>>>(vtab, W_enc, b_enc, W1,
                                                           p_src, p_dst, b1f, flags);
    // eid-major edge: 50000 waves * 16 edges = 800000 exactly
    edge_kernel<<<NWB, 256, 0, stream>>>(p_src, p_dst, src16, dst16,
                                         w2bf, b2fp, d_out, flags);
}

// Round 16
// 181.577 us; speedup vs baseline: 1.2419x; 1.2419x over previous
//
#include <hip/hip_runtime.h>
#include <hip/hip_bf16.h>
#include <stdint.h>

#define N_NODES 50000
#define N_EDGES 800000
#define D 64
#define VROWS 50048   // 782 tiles * 64 rows, rounded up for unmasked A-loads
#define CVT_BLOCKS 3125   // N_NODES*64 / (256*4) == N_EDGES / 256 exactly
#define CAP 64            // fixed bucket capacity; P(Poisson(16) > 64) ~ 1e-18

typedef __hip_bfloat16 bf16;
typedef __bf16 bf16x8 __attribute__((ext_vector_type(8)));
typedef float  f32x4  __attribute__((ext_vector_type(4)));

__device__ __forceinline__ float bu2f(unsigned short u) {
    unsigned int w = ((unsigned int)u) << 16;
    return __builtin_bit_cast(float, w);
}
__device__ __forceinline__ unsigned short f2bu(float f) {
    bf16 h = __float2bfloat16(f);           // RTNE
    return __builtin_bit_cast(unsigned short, h);
}
__device__ __forceinline__ float ldf(const void* p, size_t i, bool f32mode) {
    if (f32mode) return ((const float*)p)[i];
    return bu2f(((const unsigned short*)p)[i]);
}
__device__ __forceinline__ void stf(void* p, size_t i, float v, bool f32mode) {
    if (f32mode) ((float*)p)[i] = v;
    else ((unsigned short*)p)[i] = f2bu(v);
}
__device__ __forceinline__ int ldidx(const int* ei, size_t e, int row, bool i64mode) {
    if (i64mode) return ei[((size_t)row * N_EDGES + e) * 2];  // low word, LE
    return ei[(size_t)row * N_EDGES + e];
}
__device__ __forceinline__ void unpack8(uint4 v, float* f) {
    f[0] = bu2f(v.x & 0xffff); f[1] = bu2f(v.x >> 16);
    f[2] = bu2f(v.y & 0xffff); f[3] = bu2f(v.y >> 16);
    f[4] = bu2f(v.z & 0xffff); f[5] = bu2f(v.z >> 16);
    f[6] = bu2f(v.w & 0xffff); f[7] = bu2f(v.w >> 16);
}

// ---------------------------------------------------------------------------
// Kernel 0 (R25 init = R21 minus x-conversion): per-block dtype sniff;
// dst16/src16 extraction (coalesced, one thread per edge); counts zeroing;
// block 0 publishes params. x-conversion moved under histfill's atomic
// shadow (R15 lesson: fuse ONLY streaming work, keep host access patterns).
// ---------------------------------------------------------------------------
__global__ __launch_bounds__(256) void init_kernel(
    const void* __restrict__ x, const int* __restrict__ ei,
    const void* __restrict__ W2, const void* __restrict__ b1,
    const void* __restrict__ b2,
    int* __restrict__ flags, unsigned short* __restrict__ w2bf,
    float* __restrict__ b1f, float* __restrict__ b2fp,
    int* __restrict__ counts,
    unsigned short* __restrict__ dst16, unsigned short* __restrict__ src16)
{
    __shared__ int sh_f32m, sh_i64m;
    int tid = threadIdx.x;

    if (tid < 64) {   // wave 0: local sniff (proven detect logic)
        const unsigned short* u = (const unsigned short*)x;
        int weird = 0, zeros = 0;
        #pragma unroll
        for (int k = tid; k < 128; k += 64) {
            int ex = (u[2 * k] >> 7) & 0xFF;
            if (ex < 90 || ex > 160) ++weird;
            if (ei[2 * k + 1] == 0) ++zeros;
        }
        #pragma unroll
        for (int off = 1; off < 64; off <<= 1) {
            weird += __shfl_xor(weird, off, 64);
            zeros += __shfl_xor(zeros, off, 64);
        }
        if (tid == 0) {
            sh_f32m = (weird > 32) ? 1 : 0;
            sh_i64m = (zeros > 120) ? 1 : 0;
        }
    }
    __syncthreads();
    bool f32m = sh_f32m != 0;
    bool i64m = sh_i64m != 0;

    if (blockIdx.x == 0) {
        if (tid < 64) {
            w2bf[tid] = f2bu(ldf(W2, tid, f32m));
            b1f[tid]  = ldf(b1, tid, f32m);
        }
        if (tid == 0) {
            flags[0] = f32m ? 1 : 0;
            flags[1] = sh_i64m;
            b2fp[0] = ldf(b2, 0, f32m);
        }
    }

    // zero counts: 16 ints per block (3125 blocks * 16 = 50000 exactly)
    int cbase = blockIdx.x * 16 + (tid & 15);
    if (tid < 16 && cbase < N_NODES) counts[cbase] = 0;

    // extract edge endpoints: one thread per edge (3125*256 == N_EDGES)
    int e = blockIdx.x * 256 + tid;
    dst16[e] = (unsigned short)ldidx(ei, e, 1, i64m);
    src16[e] = (unsigned short)ldidx(ei, e, 0, i64m);
}

// ---------------------------------------------------------------------------
// Kernel 1 (R25 histfill = R14-proven body + x-convert in atomic shadow).
// R14 access patterns byte-identical: vectorized u16 dst/src reads, XCD-homed
// scatter (R11), 8 edges/thread (R12), u16 stores (R23). The ONLY addition:
// blocks < 3125 stream-convert their 1024-element x slice to bf16 xbf —
// rides in the atomic-latency stalls (R10 PMC: 19% HBM, 7% VALU headroom).
// Static slots d*CAP; atomic rank IS the slot; r<CAP is memory-safety only.
// ---------------------------------------------------------------------------
__global__ __launch_bounds__(256) void histfill_kernel(
    const void* __restrict__ x,
    const unsigned short* __restrict__ dst16,
    const unsigned short* __restrict__ src16,
    int* __restrict__ counts, unsigned short* __restrict__ sarr,
    unsigned short* __restrict__ xbf, const int* __restrict__ flags)
{
    int tid = threadIdx.x;
    int bid = blockIdx.x;

    // ---- x conversion slice (streams under the atomic stalls below) ----
    if (bid < CVT_BLOCKS) {
        bool f32m = flags[0] != 0;
        size_t idx4 = (size_t)bid * 256 + tid;
        if (f32m) {
            float4 fv = ((const float4*)x)[idx4];
            ushort4 o;
            o.x = f2bu(fv.x); o.y = f2bu(fv.y); o.z = f2bu(fv.z); o.w = f2bu(fv.w);
            ((ushort4*)xbf)[idx4] = o;
        } else {
            ((uint2*)xbf)[idx4] = ((const uint2*)x)[idx4];   // raw copy of 4 bf16
        }
    }

    // ---- R14-proven XCD-sharded scatter (byte-identical access pattern) ----
    int region = bid >> 3;
    int grp    = bid & 7;
    int e0 = region * 2048 + tid * 8;
    if (e0 >= N_EDGES) return;
    uint4 dv = *(const uint4*)(dst16 + e0);   // 8 dst ids
    uint4 sv = *(const uint4*)(src16 + e0);   // 8 src ids
    unsigned int dw[4] = {dv.x, dv.y, dv.z, dv.w};
    unsigned int sw[4] = {sv.x, sv.y, sv.z, sv.w};
    #pragma unroll
    for (int k = 0; k < 8; ++k) {
        if (e0 + k >= N_EDGES) break;
        int d = (int)((dw[k >> 1] >> ((k & 1) * 16)) & 0xffffu);
        if (((d >> 6) & 7) != grp) continue;
        int r = atomicAdd(&counts[d], 1);
        if (r < CAP)
            sarr[(size_t)d * CAP + r] =
                (unsigned short)((sw[k >> 1] >> ((k & 1) * 16)) & 0xffffu);
    }
}

// ---------------------------------------------------------------------------
// Kernel 2 (proven R15 gather, u16 sarr slots, static bucket base). One wave
// per node; lane = (f8, slot); one uint4 wave-load = 8 edge rows; 2 loads /
// 16 edges in flight; cross-slot shfl fold at the end.
// ---------------------------------------------------------------------------
__global__ __launch_bounds__(256) void gather_kernel(
    const unsigned short* __restrict__ xbf,
    const int* __restrict__ counts, const unsigned short* __restrict__ sarr,
    unsigned short* __restrict__ vtab)
{
    int w    = (blockIdx.x * 256 + threadIdx.x) >> 6;   // node id
    int lane = threadIdx.x & 63;
    if (w >= N_NODES) return;
    int cnt = counts[w];
    if (cnt > CAP) cnt = CAP;
    int beg = w * CAP, end = beg + cnt;
    int f8   = lane & 7;    // feature chunk (8 feats = 16 B)
    int slot = lane >> 3;   // edge slot 0..7

    float acc[8] = {0.f, 0.f, 0.f, 0.f, 0.f, 0.f, 0.f, 0.f};
    if (slot == 0) {   // self row, added exactly once
        uint4 q = ((const uint4*)xbf)[(size_t)w * 8 + f8];
        unpack8(q, acc);
    }

    int j = beg;
    for (; j + 16 <= end; j += 16) {
        int s0 = sarr[j + slot];
        int s1 = sarr[j + 8 + slot];
        uint4 q0 = ((const uint4*)xbf)[(size_t)s0 * 8 + f8];
        uint4 q1 = ((const uint4*)xbf)[(size_t)s1 * 8 + f8];
        float f0[8], f1[8];
        unpack8(q0, f0);
        unpack8(q1, f1);
        #pragma unroll
        for (int i = 0; i < 8; ++i) acc[i] += f0[i] + f1[i];
    }
    for (; j < end; j += 8) {
        int e = j + slot;
        bool ok = e < end;
        int s = sarr[ok ? e : beg];
        uint4 q = ((const uint4*)xbf)[(size_t)s * 8 + f8];
        float f[8];
        unpack8(q, f);
        if (ok) {
            #pragma unroll
            for (int i = 0; i < 8; ++i) acc[i] += f[i];
        }
    }

    // fold the 8 slots (lanes with equal f8) together
    #pragma unroll
    for (int i = 0; i < 8; ++i) {
        acc[i] += __shfl_xor(acc[i], 8, 64);
        acc[i] += __shfl_xor(acc[i], 16, 64);
        acc[i] += __shfl_xor(acc[i], 32, 64);
    }

    if (slot == 0) {
        uint4 o;
        o.x = (unsigned int)f2bu(acc[0]) | ((unsigned int)f2bu(acc[1]) << 16);
        o.y = (unsigned int)f2bu(acc[2]) | ((unsigned int)f2bu(acc[3]) << 16);
        o.z = (unsigned int)f2bu(acc[4]) | ((unsigned int)f2bu(acc[5]) << 16);
        o.w = (unsigned int)f2bu(acc[6]) | ((unsigned int)f2bu(acc[7]) << 16);
        ((uint4*)vtab)[(size_t)w * 8 + f8] = o;
    }
}

// ---------------------------------------------------------------------------
// Kernel 3: MFMA node transform (exact R7-proven body). One wave = 16 nodes.
// vtab aliases p_src: each wave reads its own 16 rows before overwriting.
// ---------------------------------------------------------------------------
__global__ __launch_bounds__(256) void nodemm_kernel(
    const unsigned short* vtab,
    const void* __restrict__ W_enc, const void* __restrict__ b_enc,
    const void* __restrict__ W1,
    unsigned short* p_src, unsigned short* p_dst,
    const float* __restrict__ b1f, const int* __restrict__ flags)
{
    __shared__ unsigned short wtWe[64 * 72];
    __shared__ unsigned short wtWa[64 * 72];
    __shared__ unsigned short wtWb[64 * 72];
    __shared__ float benc[64];
    __shared__ unsigned short ebuf[4][16 * 72];

    bool f32m = flags[0] != 0;
    int tid = threadIdx.x;
    for (int t = tid; t < 4096; t += 256) {
        int i = t >> 6, j = t & 63;             // W[i][j], i=k(in), j=n(out)
        wtWe[j * 72 + i] = f2bu(ldf(W_enc, t, f32m));
        wtWa[j * 72 + i] = f2bu(ldf(W1, t, f32m));
        wtWb[j * 72 + i] = f2bu(ldf(W1, 4096 + t, f32m));
    }
    if (tid < 64) benc[tid] = ldf(b_enc, tid, f32m);
    __syncthreads();

    int wave = tid >> 6;
    int lane = tid & 63;
    int lo   = lane & 15;
    int quad = lane >> 4;
    unsigned short* eb = ebuf[wave];
    int base = blockIdx.x * 64 + wave * 16;

    bf16x8 av0 = *(const bf16x8*)&vtab[(size_t)(base + lo) * D + quad * 8];
    bf16x8 av1 = *(const bf16x8*)&vtab[(size_t)(base + lo) * D + 32 + quad * 8];

    f32x4 z = {0.f, 0.f, 0.f, 0.f};
    f32x4 acc1[4] = {z, z, z, z};
    #pragma unroll
    for (int nt = 0; nt < 4; ++nt) {
        bf16x8 b0  = *(const bf16x8*)&wtWe[(nt * 16 + lo) * 72 + quad * 8];
        bf16x8 b1v = *(const bf16x8*)&wtWe[(nt * 16 + lo) * 72 + 32 + quad * 8];
        acc1[nt] = __builtin_amdgcn_mfma_f32_16x16x32_bf16(av0, b0, acc1[nt], 0, 0, 0);
        acc1[nt] = __builtin_amdgcn_mfma_f32_16x16x32_bf16(av1, b1v, acc1[nt], 0, 0, 0);
    }
    #pragma unroll
    for (int nt = 0; nt < 4; ++nt) {
        float bias = benc[nt * 16 + lo];
        #pragma unroll
        for (int r = 0; r < 4; ++r) {
            int m = quad * 4 + r;
            float ev = fmaxf(acc1[nt][r] + bias, 0.f);
            eb[m * 72 + nt * 16 + lo] = f2bu(ev);
        }
    }

    bf16x8 ae0 = *(const bf16x8*)&eb[lo * 72 + quad * 8];
    bf16x8 ae1 = *(const bf16x8*)&eb[lo * 72 + 32 + quad * 8];

    f32x4 acc2[4] = {z, z, z, z};
    f32x4 acc3[4] = {z, z, z, z};
    #pragma unroll
    for (int nt = 0; nt < 4; ++nt) {
        bf16x8 ba0 = *(const bf16x8*)&wtWa[(nt * 16 + lo) * 72 + quad * 8];
        bf16x8 ba1 = *(const bf16x8*)&wtWa[(nt * 16 + lo) * 72 + 32 + quad * 8];
        bf16x8 bb0 = *(const bf16x8*)&wtWb[(nt * 16 + lo) * 72 + quad * 8];
        bf16x8 bb1 = *(const bf16x8*)&wtWb[(nt * 16 + lo) * 72 + 32 + quad * 8];
        acc2[nt] = __builtin_amdgcn_mfma_f32_16x16x32_bf16(ae0, ba0, acc2[nt], 0, 0, 0);
        acc2[nt] = __builtin_amdgcn_mfma_f32_16x16x32_bf16(ae1, ba1, acc2[nt], 0, 0, 0);
        acc3[nt] = __builtin_amdgcn_mfma_f32_16x16x32_bf16(ae0, bb0, acc3[nt], 0, 0, 0);
        acc3[nt] = __builtin_amdgcn_mfma_f32_16x16x32_bf16(ae1, bb1, acc3[nt], 0, 0, 0);
    }
    #pragma unroll
    for (int nt = 0; nt < 4; ++nt) {
        float b1v = b1f[nt * 16 + lo];
        #pragma unroll
        for (int r = 0; r < 4; ++r) {
            int node = base + quad * 4 + r;
            if (node < N_NODES) {
                size_t idx = (size_t)node * D + nt * 16 + lo;
                p_src[idx] = f2bu(acc2[nt][r] + b1v);   // fold b1
                p_dst[idx] = f2bu(acc3[nt][r]);
            }
        }
    }
}

// ---------------------------------------------------------------------------
// Kernel 4 (proven R23: EID-MAJOR edge scorer). One wave = 16 consecutive
// edges (800000 = 50000 waves * 16 exactly). Random p_src/p_dst row reads
// (L3-resident), coalesced out[e] stores.
// ---------------------------------------------------------------------------
__global__ __launch_bounds__(256) void edge_kernel(
    const unsigned short* __restrict__ p_src,
    const unsigned short* __restrict__ p_dst,
    const unsigned short* __restrict__ src16,
    const unsigned short* __restrict__ dst16,
    const unsigned short* __restrict__ w2bf, const float* __restrict__ b2fp,
    void* __restrict__ out, const int* __restrict__ flags)
{
    bool f32m = flags[0] != 0;
    int wid  = (blockIdx.x * 256 + threadIdx.x) >> 6;   // wave id 0..49999
    int lane = threadIdx.x & 63;
    int e_base = wid * 16;
    if (e_base >= N_EDGES) return;
    int g   = lane >> 3;   // edge slot within round
    int sub = lane & 7;    // feature chunk (8 feats)

    uint4 w2v = ((const uint4*)w2bf)[sub];
    float w2[8];
    unpack8(w2v, w2);
    float bb = b2fp[0];

    int e0 = e_base + g;
    int e1 = e_base + 8 + g;
    int s0 = src16[e0], d0 = dst16[e0];
    int s1 = src16[e1], d1 = dst16[e1];

    uint4 qs0 = ((const uint4*)p_src)[(size_t)s0 * 8 + sub];
    uint4 qd0 = ((const uint4*)p_dst)[(size_t)d0 * 8 + sub];
    uint4 qs1 = ((const uint4*)p_src)[(size_t)s1 * 8 + sub];
    uint4 qd1 = ((const uint4*)p_dst)[(size_t)d1 * 8 + sub];
    float fs0[8], fd0[8], fs1[8], fd1[8];
    unpack8(qs0, fs0);
    unpack8(qd0, fd0);
    unpack8(qs1, fs1);
    unpack8(qd1, fd1);

    float c0 = 0.f, c1 = 0.f;
    #pragma unroll
    for (int i = 0; i < 8; ++i) {
        c0 += fmaxf(fs0[i] + fd0[i], 0.f) * w2[i];
        c1 += fmaxf(fs1[i] + fd1[i], 0.f) * w2[i];
    }
    c0 += __shfl_xor(c0, 1, 64);
    c0 += __shfl_xor(c0, 2, 64);
    c0 += __shfl_xor(c0, 4, 64);
    c1 += __shfl_xor(c1, 1, 64);
    c1 += __shfl_xor(c1, 2, 64);
    c1 += __shfl_xor(c1, 4, 64);
    if (sub == 0) {
        stf(out, e0, c0 + bb, f32m);   // 8 consecutive eids per round:
        stf(out, e1, c1 + bb, f32m);   // coalesced 32B segments
    }
}

// ---------------------------------------------------------------------------
extern "C" void kernel_launch(void* const* d_in, const int* in_sizes, int n_in,
                              void* d_out, int out_size, void* d_ws, size_t ws_size,
                              hipStream_t stream)
{
    const void* x     = d_in[0];
    const int*  ei    = (const int*)d_in[1];
    const void* W_enc = d_in[2];
    const void* b_enc = d_in[3];
    const void* W1    = d_in[4];
    const void* b1    = d_in[5];
    const void* W2    = d_in[6];
    const void* b2    = d_in[7];

    const size_t NTv  = (size_t)VROWS * D;     // 3,203,072 elements
    const size_t NCAP = (size_t)N_NODES * CAP; // 3,200,000 slots
    // ws layout (~29.2 MB):
    unsigned short* p_src = (unsigned short*)d_ws;       // 6.41 MB (aliases vtab)
    unsigned short* p_dst = p_src + NTv;                 // 6.41 MB
    unsigned short* xbf   = p_dst + NTv;                 // 6.41 MB (bf16 x table)
    unsigned short* sarr  = xbf + NTv;                   // 6.40 MB (u16 src per slot)
    float* b1f     = (float*)(sarr + NCAP);              // 256 B
    unsigned short* w2bf = (unsigned short*)(b1f + 64);  // 128 B
    float* b2fp    = (float*)(w2bf + 64);                // 16 B
    int*   counts  = (int*)(b2fp + 4);                   // 200 KB
    int*   flags   = counts + N_NODES;                   // 32 B (padded for align)
    unsigned short* dst16 = (unsigned short*)(flags + 8); // 1.6 MB (16B-aligned)
    unsigned short* src16 = dst16 + N_EDGES;             // 1.6 MB

    unsigned short* vtab = p_src;   // alias: v-rows live here until nodemm

    init_kernel<<<CVT_BLOCKS, 256, 0, stream>>>(x, ei, W2, b1, b2, flags, w2bf,
                                                b1f, b2fp, counts, dst16, src16);

    const int HF_BLOCKS = ((N_EDGES + 2047) / 2048) * 8;   // 391*8 = 3128
    histfill_kernel<<<HF_BLOCKS, 256, 0, stream>>>(x, dst16, src16, counts, sarr,
                                                   xbf, flags);

    const int NWB = (N_NODES * 64 + 255) / 256;  // 12500 (1 wave/node)
    gather_kernel<<<NWB, 256, 0, stream>>>(xbf, counts, sarr, vtab);
    nodemm_kernel<<<(N_NODES + 63) / 64, 256, 0, stream>>>(vtab, W_enc, b_enc, W1,
                                                           p_src, p_dst, b1f, flags);
    // eid-major edge: 50000 waves * 16 edges = 800000 exactly
    edge_kernel<<<NWB, 256, 0, stream>>>(p_src, p_dst, src16, dst16,
                                         w2bf, b2fp, d_out, flags);
}